// Round 5
// baseline (274.456 us; speedup 1.0000x reference)
//
#include <hip/hip_runtime.h>

// Problem constants (from reference)
constexpr int kB   = 128;
constexpr int kU   = 4;
constexpr int kNBS = 64;
constexpr int kS   = 408;
constexpr int kS4  = kS / 4;                               // 102 float4 per row
constexpr int kRowsPerTile   = 4;                          // 16 NT loads per tile
constexpr int kTilesPerThread = 4;                         // 16 NBS rows per thread
constexpr unsigned kThreads =
    (unsigned)kB * kU * (kNBS / (kRowsPerTile * kTilesPerThread)) * kS4; // 208,896
constexpr float kEmW     = 0.01f;
constexpr float kInvNRad = 1.0f / ((float)kB * kU * kNBS * kS);
constexpr float kInvNAtt = 1.0f / ((float)kB * kU * kS);

// Native clang vector type — required by __builtin_nontemporal_load.
typedef float vfloat4 __attribute__((ext_vector_type(4)));

// R13: software-pipelined rewrite of the R8/R12 champion (44.2-44.9 us).
//
// Session ledger:
//  R8/R12 (256,3), NT, chunk=8 one-shot: 44.2-44.9 us, VGPR=84  <- champion
//  R9  plain loads (no NT):              79.5 us — L2 thrash. Keep NT.
//  R11 (256,6):                         126.0 us — spills (WRITE=162MB).
//
// R12 insight: VGPR=84 with a "32-load batch" proves the scheduler already
// sinks loads (~half-batch in flight). The real residual inefficiency is
// structural: one-shot waves issue->drain->compute->die in lockstep
// (12 waves/CU start each generation together), anti-correlating memory
// and VALU phases (HBM 2.67 TB/s, VALUBusy 23%, occupancy 21% — nothing
// saturated). This version makes each thread a 4-stage pipeline over
// 4-row tiles with double-buffered registers: tile t+1's 16 NT loads are
// issued before tile t is consumed, so loads stay in flight continuously.
// Grid: 816 blocks = 1.06 generations at 3 blocks/CU (near-persistent).
// Math is bit-identical to champion. Tripwires: WRITE_SIZE ~51 KB,
// VGPR_Count 120-168 (spill -> revert to R12).
//
// Mapping: tid in [0, 208896).
//   s4  = tid % 102                    (fastest dim -> coalesced)
//   rem = tid / 102  in [0, 2048)
//   sub = rem % 4, bu = rem / 4        (bu in [0,512) = b*U+u)
//   rows r = bu*64 + sub*16 + t*4 + j, t=0..3, j=0..3; q = r*102 + s4
//   atten a = bu*102 + s4 — loaded once, reused for all 16 rows.
__global__ void __launch_bounds__(256, 3)
prism_loss_kernel(const vfloat4* __restrict__ atten_re,
                  const vfloat4* __restrict__ atten_im,
                  const vfloat4* __restrict__ rad_re,
                  const vfloat4* __restrict__ rad_im,
                  const vfloat4* __restrict__ tgt_re,
                  const vfloat4* __restrict__ tgt_im,
                  const vfloat4* __restrict__ weights,
                  float* __restrict__ out)
{
    const unsigned tid   = blockIdx.x * 256 + threadIdx.x;  // grid sized exactly
    const unsigned rem   = tid / 102u;                      // magic-mul div
    const unsigned s4    = tid - rem * 102u;
    const unsigned sub   = rem & 3u;
    const unsigned bu    = rem >> 2;
    const unsigned qbase = (bu * 64u + sub * 16u) * 102u + s4;
    const unsigned abase = bu * 102u + s4;
    const bool do_att = (sub == 0u);

    const vfloat4 w  = weights[s4];
    const vfloat4 ar = atten_re[abase];
    const vfloat4 ai = atten_im[abase];

    // Double-buffered tile registers: 2 x 16 x vfloat4 = 128 VGPRs payload.
    // All indices are compile-time constants after full unroll (no scratch).
    vfloat4 rr[2][4], ri[2][4], tr[2][4], ti[2][4];

    // Prologue: tile 0 -> buffer 0.
    #pragma unroll
    for (int j = 0; j < 4; ++j) {
        const unsigned qq = qbase + (unsigned)j * 102u;
        rr[0][j] = __builtin_nontemporal_load(&rad_re[qq]);
        ri[0][j] = __builtin_nontemporal_load(&rad_im[qq]);
        tr[0][j] = __builtin_nontemporal_load(&tgt_re[qq]);
        ti[0][j] = __builtin_nontemporal_load(&tgt_im[qq]);
    }

    float recv   = 0.0f;
    float em_rad = 0.0f;
    float em_att = 0.0f;

    #pragma unroll
    for (int t = 0; t < kTilesPerThread; ++t) {
        const int cur = t & 1;
        const int nxt = cur ^ 1;

        // Issue next tile's loads before consuming the current tile.
        if (t < kTilesPerThread - 1) {
            const unsigned qn = qbase + (unsigned)(t + 1) * (4u * 102u);
            #pragma unroll
            for (int j = 0; j < 4; ++j) {
                const unsigned qq = qn + (unsigned)j * 102u;
                rr[nxt][j] = __builtin_nontemporal_load(&rad_re[qq]);
                ri[nxt][j] = __builtin_nontemporal_load(&rad_im[qq]);
                tr[nxt][j] = __builtin_nontemporal_load(&tgt_re[qq]);
                ti[nxt][j] = __builtin_nontemporal_load(&tgt_im[qq]);
            }
        }

        // Consume current tile in issue order -> incremental vmcnt waits.
        #pragma unroll
        for (int j = 0; j < 4; ++j) {
            #pragma unroll
            for (int c = 0; c < 4; ++c) {
                const float a_r = ar[c], a_i = ai[c];
                const float r_r = rr[cur][j][c], r_i = ri[cur][j][c];
                const float pr = a_r * r_r - a_i * r_i;
                const float pi = a_r * r_i + a_i * r_r;
                const float dr = pr - tr[cur][j][c];
                const float di = pi - ti[cur][j][c];
                recv = fmaf((dr * dr + di * di), w[c], recv);
                float rm = sqrtf(fmaf(r_r, r_r, r_i * r_i)) - 10.0f;
                rm = fmaxf(rm, 0.0f);
                em_rad = fmaf(rm, rm, em_rad);
            }
        }
    }

    if (do_att) {
        #pragma unroll
        for (int c = 0; c < 4; ++c) {
            float am = sqrtf(fmaf(ar[c], ar[c], ai[c] * ai[c])) - 1.0f;
            am = fmaxf(am, 0.0f);
            em_att = fmaf(am, am, em_att);
        }
    }

    float acc = recv + kEmW * (em_rad * kInvNRad + em_att * kInvNAtt);

    // Wave-64 reduction.
    #pragma unroll
    for (int off = 32; off > 0; off >>= 1)
        acc += __shfl_down(acc, off, 64);

    __shared__ float sdata[4];
    const int lane = threadIdx.x & 63;
    const int wave = threadIdx.x >> 6;
    if (lane == 0) sdata[wave] = acc;
    __syncthreads();
    if (threadIdx.x == 0) {
        atomicAdd(out, sdata[0] + sdata[1] + sdata[2] + sdata[3]);
    }
}

extern "C" void kernel_launch(void* const* d_in, const int* in_sizes, int n_in,
                              void* d_out, int out_size, void* d_ws, size_t ws_size,
                              hipStream_t stream) {
    const vfloat4* atten_re = (const vfloat4*)d_in[0];
    const vfloat4* atten_im = (const vfloat4*)d_in[1];
    const vfloat4* rad_re   = (const vfloat4*)d_in[2];
    const vfloat4* rad_im   = (const vfloat4*)d_in[3];
    const vfloat4* tgt_re   = (const vfloat4*)d_in[4];
    const vfloat4* tgt_im   = (const vfloat4*)d_in[5];
    const vfloat4* weights  = (const vfloat4*)d_in[6];
    float* out = (float*)d_out;

    // d_out is re-poisoned to 0xAA before every timed launch; zero it.
    (void)hipMemsetAsync(out, 0, sizeof(float), stream);

    // 816 blocks * 256 threads == kThreads exactly (no bounds checks needed).
    prism_loss_kernel<<<(int)(kThreads / 256), 256, 0, stream>>>(
        atten_re, atten_im, rad_re, rad_im, tgt_re, tgt_im, weights, out);
}